// Round 6
// baseline (1854.389 us; speedup 1.0000x reference)
//
#include <hip/hip_runtime.h>

#define NNODES 50000
#define HID 128
#define NREL 9
#define NLAYERS 3
#define NEDGES 600000

#define NBINS (NREL * NNODES)          // 450000, binned [rel][dest]
#define SCAN_CHUNK 1024
#define NBLK ((NBINS + SCAN_CHUNK - 1) / SCAN_CHUNK)   // 440

#define GM 64                           // dest rows per block
#define SP 132                          // Sacc fp32 pitch: 528 B rows, 16B-aligned
#define WPITCH 136                      // Ws bf16 pitch

typedef __attribute__((ext_vector_type(8))) short short8;
typedef __attribute__((ext_vector_type(4))) float f32x4;

__device__ __forceinline__ short f2bf(float f) {
    union { float f; unsigned u; } c; c.f = f;
    unsigned r = c.u + 0x7fff + ((c.u >> 16) & 1);   // RNE
    return (short)(r >> 16);
}

// ---------------- CSR build: counting sort by (rel, dest) ----------------

__global__ void hist2_kernel(const int* __restrict__ dst, const int* __restrict__ etype,
                             int* __restrict__ bins) {
    int e = blockIdx.x * blockDim.x + threadIdx.x;
    if (e < NEDGES) {
        int bin = etype[e] * NNODES + dst[e];
        atomicAdd(&bins[bin], 1);
    }
}

__global__ __launch_bounds__(256) void scan_pass1(const int* __restrict__ bins,
                                                  int* __restrict__ blocksum) {
    __shared__ int red[256];
    int b = blockIdx.x, t = threadIdx.x;
    int i0 = b * SCAN_CHUNK + t * 4;
    int s = 0;
#pragma unroll
    for (int k = 0; k < 4; k++)
        if (i0 + k < NBINS) s += bins[i0 + k];
    red[t] = s;
    __syncthreads();
    for (int off = 128; off > 0; off >>= 1) {
        if (t < off) red[t] += red[t + off];
        __syncthreads();
    }
    if (t == 0) blocksum[b] = red[0];
}

__global__ __launch_bounds__(512) void scan_pass2(const int* __restrict__ blocksum,
                                                  int* __restrict__ blockoff,
                                                  int* __restrict__ rowptr) {
    __shared__ int s[512];
    int t = threadIdx.x;
    int v = (t < NBLK) ? blocksum[t] : 0;
    s[t] = v;
    __syncthreads();
    for (int off = 1; off < 512; off <<= 1) {
        int x = (t >= off) ? s[t - off] : 0;
        __syncthreads();
        s[t] += x;
        __syncthreads();
    }
    if (t < NBLK) blockoff[t] = s[t] - v;
    if (t == 0) rowptr[NBINS] = NEDGES;
}

__global__ __launch_bounds__(256) void scan_pass3(const int* __restrict__ bins,
                                                  const int* __restrict__ blockoff,
                                                  int* __restrict__ rowptr,
                                                  int* __restrict__ cursor) {
    __shared__ int sc[256];
    int b = blockIdx.x, t = threadIdx.x;
    int i0 = b * SCAN_CHUNK + t * 4;
    int v[4], p[4];
    int s = 0;
#pragma unroll
    for (int k = 0; k < 4; k++) {
        v[k] = (i0 + k < NBINS) ? bins[i0 + k] : 0;
        p[k] = s;
        s += v[k];
    }
    sc[t] = s;
    __syncthreads();
    for (int off = 1; off < 256; off <<= 1) {
        int x = (t >= off) ? sc[t - off] : 0;
        __syncthreads();
        sc[t] += x;
        __syncthreads();
    }
    int base = blockoff[b] + (sc[t] - s);
#pragma unroll
    for (int k = 0; k < 4; k++) {
        if (i0 + k < NBINS) {
            rowptr[i0 + k] = base + p[k];
            cursor[i0 + k] = base + p[k];
        }
    }
}

__global__ void place_kernel(const int* __restrict__ dst, const int* __restrict__ src,
                             const int* __restrict__ etype,
                             int* __restrict__ cursor, int2* __restrict__ bpack) {
    int e = blockIdx.x * blockDim.x + threadIdx.x;
    if (e < NEDGES) {
        int d = dst[e];
        int bin = etype[e] * NNODES + d;
        int pos = atomicAdd(&cursor[bin], 1);
        bpack[pos] = make_int2(src[e], d);
    }
}

// ---------------- W transpose+convert: Wt[l,r][n][k] = bf16(W[l,r][k][n]) ----------------

__global__ __launch_bounds__(256) void convert_w(const float* __restrict__ W,
                                                 short* __restrict__ Wt) {
    int lr = blockIdx.x;
    const float* w = W + (size_t)lr * HID * HID;
    short* o = Wt + (size_t)lr * HID * HID;
    int tid = threadIdx.x;
#pragma unroll 4
    for (int i = 0; i < 64; i++) {
        int elem = i * 256 + tid;
        int k = elem >> 7, n = elem & 127;
        o[n * HID + k] = f2bf(w[elem]);
    }
}

// ---------------- fused layer: Hout[d] = relu?( sum_r S_r[d] @ W_r + c_{r,d} b_r ) ----------------
// Edge-parallel: per relation, block's edge range is contiguous; 16-lane groups
// scatter Hin[src] rows into LDS fp32 accumulators via ds_add_f32 (fire-and-forget).

__global__ __launch_bounds__(256) void fused_layer(const float* __restrict__ Hin,
                                                   const short* __restrict__ Wt,   // [9][n][k] bf16
                                                   const float* __restrict__ Bias, // [9][128]
                                                   const int2* __restrict__ bpack, // (src,dst)
                                                   const int* __restrict__ rowptr, // [r*N+d]
                                                   float* __restrict__ Hout,
                                                   int relu_out) {
    __shared__ float Sacc[GM][SP];
    __shared__ short Ws[HID][WPITCH];
    __shared__ int   cnt_s[NREL][GM];

    int tid  = threadIdx.x;
    int wave = tid >> 6, lane = tid & 63;
    int row0 = blockIdx.x * GM;
    int rows = (NNODES - row0 < GM) ? (NNODES - row0) : GM;
    int m0   = wave * 16;
    int lm = lane & 15, lq = lane >> 4;

    int grp = tid >> 4;          // 0..15 edge-parallel groups
    int l16 = tid & 15;

    f32x4 acc[8];
#pragma unroll
    for (int nt = 0; nt < 8; nt++) acc[nt] = (f32x4){0.f, 0.f, 0.f, 0.f};

    for (int r = 0; r < NREL; r++) {
        __syncthreads();   // prev MFMA reads of Sacc/Ws complete

        // ---- zero Sacc (each thread: one row-quarter = 8 float4) ----
        {
            int zr = tid >> 2, zc = (tid & 3) * 32;
#pragma unroll
            for (int j = 0; j < 32; j += 4)
                *(float4*)&Sacc[zr][zc + j] = make_float4(0.f, 0.f, 0.f, 0.f);
        }
        // ---- stage W_r ----
        {
            const short* wr = Wt + (size_t)r * HID * HID;
#pragma unroll
            for (int i = 0; i < 8; i++) {
                int elem = i * 2048 + tid * 8;
                short8 v = *(const short8*)(wr + elem);
                int n = elem >> 7, k = elem & 127;
                *(short8*)&Ws[n][k] = v;
            }
        }
        // ---- counts for bias epilogue ----
        if (tid < GM) {
            int d = row0 + tid;
            int c = 0;
            if (d < NNODES) {
                int b = r * NNODES + d;
                c = rowptr[b + 1] - rowptr[b];
            }
            cnt_s[r][tid] = c;
        }
        __syncthreads();

        // ---- edge-parallel aggregate ----
        int jlo = rowptr[r * NNODES + row0];
        int jhi = rowptr[r * NNODES + row0 + rows];
        for (int j = jlo + grp; j < jhi; j += 16) {
            int2 sd = bpack[j];
            int dl = sd.y - row0;
            const float* hp = Hin + (size_t)sd.x * HID + l16 * 8;
            float4 v0 = *(const float4*)hp;
            float4 v1 = *(const float4*)(hp + 4);
            float* dp = &Sacc[dl][l16 * 8];
            atomicAdd(dp + 0, v0.x);
            atomicAdd(dp + 1, v0.y);
            atomicAdd(dp + 2, v0.z);
            atomicAdd(dp + 3, v0.w);
            atomicAdd(dp + 4, v1.x);
            atomicAdd(dp + 5, v1.y);
            atomicAdd(dp + 6, v1.z);
            atomicAdd(dp + 7, v1.w);
        }
        __syncthreads();

        // ---- MFMA: acc += bf16(Sacc) @ W_r ----
        short8 af[4];
#pragma unroll
        for (int ks = 0; ks < 4; ks++) {
            const float* sp = &Sacc[m0 + lm][ks * 32 + lq * 8];
            float4 f0 = *(const float4*)sp;
            float4 f1 = *(const float4*)(sp + 4);
            short8 a = {f2bf(f0.x), f2bf(f0.y), f2bf(f0.z), f2bf(f0.w),
                        f2bf(f1.x), f2bf(f1.y), f2bf(f1.z), f2bf(f1.w)};
            af[ks] = a;
        }
#pragma unroll
        for (int nt = 0; nt < 8; nt++) {
#pragma unroll
            for (int ks = 0; ks < 4; ks++) {
                short8 bf = *(const short8*)&Ws[nt * 16 + lm][ks * 32 + lq * 8];
                acc[nt] = __builtin_amdgcn_mfma_f32_16x16x32_bf16(af[ks], bf, acc[nt], 0, 0, 0);
            }
        }
    }

    // ---- epilogue: + sum_r cnt*bias, relu?, store fp32 ----
    // C/D layout: col = lane&15, row = lq*4 + reg
#pragma unroll
    for (int nt = 0; nt < 8; nt++) {
        int n = nt * 16 + lm;
        float bv[NREL];
#pragma unroll
        for (int r = 0; r < NREL; r++) bv[r] = Bias[r * HID + n];
#pragma unroll
        for (int reg = 0; reg < 4; reg++) {
            int rl = m0 + lq * 4 + reg;
            int d = row0 + rl;
            if (d < NNODES) {
                float b = 0.f;
#pragma unroll
                for (int r = 0; r < NREL; r++) b += (float)cnt_s[r][rl] * bv[r];
                float o = acc[nt][reg] + b;
                if (relu_out) o = fmaxf(o, 0.f);
                Hout[(size_t)d * HID + n] = o;
            }
        }
    }
}

// ---------------- driver ----------------

extern "C" void kernel_launch(void* const* d_in, const int* in_sizes, int n_in,
                              void* d_out, int out_size, void* d_ws, size_t ws_size,
                              hipStream_t stream) {
    const int*   edge_index = (const int*)d_in[0];   // [2, NEDGES]: row0=dest, row1=src
    const int*   etype      = (const int*)d_in[1];
    const float* emb        = (const float*)d_in[2];
    const float* W          = (const float*)d_in[3]; // [3,9,128,128]
    const float* Bias       = (const float*)d_in[4]; // [3,9,128]
    float*       out        = (float*)d_out;

    const int* dst  = edge_index;
    const int* srcA = edge_index + NEDGES;

    // ws layout
    float* HA = (float*)d_ws;                               // 50000*128 f32
    float* HB = HA + (size_t)NNODES * HID;                  // 50000*128 f32
    short* Wt = (short*)(HB + (size_t)NNODES * HID);        // 27*128*128 bf16
    int2*  bpack    = (int2*)(Wt + (size_t)NLAYERS * NREL * HID * HID);
    int*   bins     = (int*)(bpack + NEDGES);
    int*   cursor   = bins + NBINS;
    int*   rowptr   = cursor + NBINS;                       // NBINS+1
    int*   blocksum = rowptr + NBINS + 1;
    int*   blockoff = blocksum + NBLK;

    hipMemsetAsync(bins, 0, NBINS * sizeof(int), stream);
    hist2_kernel<<<(NEDGES + 255) / 256, 256, 0, stream>>>(dst, etype, bins);
    scan_pass1<<<NBLK, 256, 0, stream>>>(bins, blocksum);
    scan_pass2<<<1, 512, 0, stream>>>(blocksum, blockoff, rowptr);
    scan_pass3<<<NBLK, 256, 0, stream>>>(bins, blockoff, rowptr, cursor);
    place_kernel<<<(NEDGES + 255) / 256, 256, 0, stream>>>(dst, srcA, etype, cursor, bpack);
    convert_w<<<NLAYERS * NREL, 256, 0, stream>>>(W, Wt);

    const float* Hin = emb;
    for (int l = 0; l < NLAYERS; l++) {
        float* Hout = (l == 0) ? HA : ((l == 1) ? HB : out);
        const short* Wtl = Wt + (size_t)l * NREL * HID * HID;
        const float* Bl  = Bias + (size_t)l * NREL * HID;
        fused_layer<<<(NNODES + GM - 1) / GM, 256, 0, stream>>>(
            Hin, Wtl, Bl, bpack, rowptr, Hout, (l + 1 < NLAYERS) ? 1 : 0);
        Hin = Hout;
    }
}

// Round 7
// 749.650 us; speedup vs baseline: 2.4737x; 2.4737x over previous
//
#include <hip/hip_runtime.h>

#define NNODES 50000
#define HID 128
#define NREL 9
#define NLAYERS 3
#define NEDGES 600000

#define NBINS (NREL * NNODES)          // 450000, binned [dest][rel]
#define SCAN_CHUNK 1024
#define NBLK ((NBINS + SCAN_CHUNK - 1) / SCAN_CHUNK)   // 440

#define GM 64                           // dest rows per block
#define APITCH 136                      // Ss bf16 pitch (272 B rows, 16B-aligned)
#define SRCCAP 1536                     // LDS src-index buffer (block avg ~768 edges)

typedef __attribute__((ext_vector_type(8))) short short8;
typedef __attribute__((ext_vector_type(4))) float f32x4;

__device__ __forceinline__ short f2bf(float f) {
    union { float f; unsigned u; } c; c.f = f;
    unsigned r = c.u + 0x7fff + ((c.u >> 16) & 1);   // RNE
    return (short)(r >> 16);
}

// ---------------- CSR build: counting sort by (dest, rel) ----------------

__global__ void hist2_kernel(const int* __restrict__ dst, const int* __restrict__ etype,
                             int* __restrict__ bins) {
    int e = blockIdx.x * blockDim.x + threadIdx.x;
    if (e < NEDGES) {
        int bin = dst[e] * NREL + etype[e];
        atomicAdd(&bins[bin], 1);
    }
}

__global__ __launch_bounds__(256) void scan_pass1(const int* __restrict__ bins,
                                                  int* __restrict__ blocksum) {
    __shared__ int red[256];
    int b = blockIdx.x, t = threadIdx.x;
    int i0 = b * SCAN_CHUNK + t * 4;
    int s = 0;
#pragma unroll
    for (int k = 0; k < 4; k++)
        if (i0 + k < NBINS) s += bins[i0 + k];
    red[t] = s;
    __syncthreads();
    for (int off = 128; off > 0; off >>= 1) {
        if (t < off) red[t] += red[t + off];
        __syncthreads();
    }
    if (t == 0) blocksum[b] = red[0];
}

__global__ __launch_bounds__(512) void scan_pass2(const int* __restrict__ blocksum,
                                                  int* __restrict__ blockoff,
                                                  int* __restrict__ rowptr) {
    __shared__ int s[512];
    int t = threadIdx.x;
    int v = (t < NBLK) ? blocksum[t] : 0;
    s[t] = v;
    __syncthreads();
    for (int off = 1; off < 512; off <<= 1) {
        int x = (t >= off) ? s[t - off] : 0;
        __syncthreads();
        s[t] += x;
        __syncthreads();
    }
    if (t < NBLK) blockoff[t] = s[t] - v;
    if (t == 0) rowptr[NBINS] = NEDGES;
}

__global__ __launch_bounds__(256) void scan_pass3(const int* __restrict__ bins,
                                                  const int* __restrict__ blockoff,
                                                  int* __restrict__ rowptr,
                                                  int* __restrict__ cursor) {
    __shared__ int sc[256];
    int b = blockIdx.x, t = threadIdx.x;
    int i0 = b * SCAN_CHUNK + t * 4;
    int v[4], p[4];
    int s = 0;
#pragma unroll
    for (int k = 0; k < 4; k++) {
        v[k] = (i0 + k < NBINS) ? bins[i0 + k] : 0;
        p[k] = s;
        s += v[k];
    }
    sc[t] = s;
    __syncthreads();
    for (int off = 1; off < 256; off <<= 1) {
        int x = (t >= off) ? sc[t - off] : 0;
        __syncthreads();
        sc[t] += x;
        __syncthreads();
    }
    int base = blockoff[b] + (sc[t] - s);
#pragma unroll
    for (int k = 0; k < 4; k++) {
        if (i0 + k < NBINS) {
            rowptr[i0 + k] = base + p[k];
            cursor[i0 + k] = base + p[k];
        }
    }
}

__global__ void place_kernel(const int* __restrict__ dst, const int* __restrict__ src,
                             const int* __restrict__ etype,
                             int* __restrict__ cursor, int* __restrict__ bsrc) {
    int e = blockIdx.x * blockDim.x + threadIdx.x;
    if (e < NEDGES) {
        int bin = dst[e] * NREL + etype[e];
        int pos = atomicAdd(&cursor[bin], 1);
        bsrc[pos] = src[e];
    }
}

// ---------------- W transpose+convert: Wt[l,r][n][k] = bf16(W[l,r][k][n]) ----------------

__global__ __launch_bounds__(256) void convert_w(const float* __restrict__ W,
                                                 short* __restrict__ Wt) {
    int lr = blockIdx.x;
    const float* w = W + (size_t)lr * HID * HID;
    short* o = Wt + (size_t)lr * HID * HID;
    int tid = threadIdx.x;
#pragma unroll 4
    for (int i = 0; i < 64; i++) {
        int elem = i * 256 + tid;
        int k = elem >> 7, n = elem & 127;
        o[n * HID + k] = f2bf(w[elem]);
    }
}

// ---------------- fused layer ----------------
// Hout[d] = relu?( sum_r S_r[d] @ W_r + cnt_{d,r} b_r ),  S_r[d] = sum_{e in CSR(d,r)} Hin[src_e]
// Per wave: 16 dests; aggregation = 16 independent lane-group chains (4 lanes/dest,
// 32 floats/lane), src indices pre-staged in LDS. B-fragments read directly from
// global (W_r is L1/L2-resident). No atomics anywhere.

__global__ __launch_bounds__(256) void fused_layer(const float* __restrict__ Hin,
                                                   const short* __restrict__ Wt,   // [9][n][k] bf16
                                                   const float* __restrict__ Bias, // [9][128]
                                                   const int* __restrict__ bsrc,
                                                   const int* __restrict__ rowptr, // [d*9+r]
                                                   float* __restrict__ Hout,
                                                   int relu_out) {
    __shared__ short Ss[GM][APITCH];            // 17408 B
    __shared__ int   rp_s[GM * NREL + 1];       // 2308 B
    __shared__ int   srcbuf[SRCCAP];            // 6144 B
    __shared__ float bias_s[NREL * HID];        // 4608 B

    int tid  = threadIdx.x;
    int wave = tid >> 6, lane = tid & 63;
    int row0 = blockIdx.x * GM;
    int m0   = wave * 16;
    int lm = lane & 15, lq = lane >> 4;

    // ---- phase 0: stage rowptr slab, src indices, bias ----
    int rpbase = row0 * NREL;
    for (int i = tid; i <= GM * NREL; i += 256) {
        int g = rpbase + i;
        rp_s[i] = rowptr[(g < NBINS) ? g : NBINS];
    }
    for (int i = tid; i < NREL * HID; i += 256) bias_s[i] = Bias[i];
    __syncthreads();
    int jbase = rp_s[0];
    int nsrc  = rp_s[GM * NREL] - jbase;
    int ncap  = (nsrc < SRCCAP) ? nsrc : SRCCAP;
    for (int i = tid; i < ncap; i += 256) srcbuf[i] = bsrc[jbase + i];

    f32x4 acc[8];
#pragma unroll
    for (int nt = 0; nt < 8; nt++) acc[nt] = (f32x4){0.f, 0.f, 0.f, 0.f};

    int dl = m0 + (lane >> 2);     // this lane's dest (0..63 in block)
    int q  = lane & 3;             // 32-float chunk within the row

    for (int r = 0; r < NREL; r++) {
        __syncthreads();           // srcbuf staged (r=0) / prev MFMA's Ss reads done

        // ---- aggregate: 16 independent dest-chains per wave ----
        int rs = rp_s[dl * NREL + r] - jbase;
        int re = rp_s[dl * NREL + r + 1] - jbase;
        float4 s0 = make_float4(0.f,0.f,0.f,0.f), s1 = s0, s2 = s0, s3 = s0;
        float4 s4 = s0, s5 = s0, s6 = s0, s7 = s0;
        for (int j = rs; j < re; j++) {
            int sidx;
            if (j < SRCCAP) sidx = srcbuf[j];
            else            sidx = bsrc[jbase + j];
            const float* hp = Hin + (size_t)sidx * HID + q * 32;
            float4 v0 = *(const float4*)(hp +  0);
            float4 v1 = *(const float4*)(hp +  4);
            float4 v2 = *(const float4*)(hp +  8);
            float4 v3 = *(const float4*)(hp + 12);
            float4 v4 = *(const float4*)(hp + 16);
            float4 v5 = *(const float4*)(hp + 20);
            float4 v6 = *(const float4*)(hp + 24);
            float4 v7 = *(const float4*)(hp + 28);
            s0.x += v0.x; s0.y += v0.y; s0.z += v0.z; s0.w += v0.w;
            s1.x += v1.x; s1.y += v1.y; s1.z += v1.z; s1.w += v1.w;
            s2.x += v2.x; s2.y += v2.y; s2.z += v2.z; s2.w += v2.w;
            s3.x += v3.x; s3.y += v3.y; s3.z += v3.z; s3.w += v3.w;
            s4.x += v4.x; s4.y += v4.y; s4.z += v4.z; s4.w += v4.w;
            s5.x += v5.x; s5.y += v5.y; s5.z += v5.z; s5.w += v5.w;
            s6.x += v6.x; s6.y += v6.y; s6.z += v6.z; s6.w += v6.w;
            s7.x += v7.x; s7.y += v7.y; s7.z += v7.z; s7.w += v7.w;
        }
        short8 p0 = {f2bf(s0.x), f2bf(s0.y), f2bf(s0.z), f2bf(s0.w),
                     f2bf(s1.x), f2bf(s1.y), f2bf(s1.z), f2bf(s1.w)};
        short8 p1 = {f2bf(s2.x), f2bf(s2.y), f2bf(s2.z), f2bf(s2.w),
                     f2bf(s3.x), f2bf(s3.y), f2bf(s3.z), f2bf(s3.w)};
        short8 p2 = {f2bf(s4.x), f2bf(s4.y), f2bf(s4.z), f2bf(s4.w),
                     f2bf(s5.x), f2bf(s5.y), f2bf(s5.z), f2bf(s5.w)};
        short8 p3 = {f2bf(s6.x), f2bf(s6.y), f2bf(s6.z), f2bf(s6.w),
                     f2bf(s7.x), f2bf(s7.y), f2bf(s7.z), f2bf(s7.w)};
        *(short8*)&Ss[dl][q * 32 +  0] = p0;
        *(short8*)&Ss[dl][q * 32 +  8] = p1;
        *(short8*)&Ss[dl][q * 32 + 16] = p2;
        *(short8*)&Ss[dl][q * 32 + 24] = p3;
        __syncthreads();

        // ---- MFMA: acc += Ss(tile) @ W_r, B-fragments straight from global ----
        const short* wr = Wt + (size_t)r * HID * HID;
        short8 af[4];
#pragma unroll
        for (int ks = 0; ks < 4; ks++)
            af[ks] = *(const short8*)&Ss[m0 + lm][ks * 32 + lq * 8];
#pragma unroll
        for (int nt = 0; nt < 8; nt++) {
#pragma unroll
            for (int ks = 0; ks < 4; ks++) {
                short8 bf = *(const short8*)(wr + (nt * 16 + lm) * HID + ks * 32 + lq * 8);
                acc[nt] = __builtin_amdgcn_mfma_f32_16x16x32_bf16(af[ks], bf, acc[nt], 0, 0, 0);
            }
        }
    }

    // ---- epilogue: + sum_r cnt*bias, relu?, store fp32 ----
    // C/D layout: col = lane&15, row = lq*4 + reg
#pragma unroll
    for (int reg = 0; reg < 4; reg++) {
        int rl = m0 + lq * 4 + reg;
        int d  = row0 + rl;
        if (d >= NNODES) continue;
        int cr[NREL];
#pragma unroll
        for (int r = 0; r < NREL; r++)
            cr[r] = rp_s[rl * NREL + r + 1] - rp_s[rl * NREL + r];
#pragma unroll
        for (int nt = 0; nt < 8; nt++) {
            int n = nt * 16 + lm;
            float b = 0.f;
#pragma unroll
            for (int r = 0; r < NREL; r++) b += (float)cr[r] * bias_s[r * HID + n];
            float o = acc[nt][reg] + b;
            if (relu_out) o = fmaxf(o, 0.f);
            Hout[(size_t)d * HID + n] = o;
        }
    }
}

// ---------------- driver ----------------

extern "C" void kernel_launch(void* const* d_in, const int* in_sizes, int n_in,
                              void* d_out, int out_size, void* d_ws, size_t ws_size,
                              hipStream_t stream) {
    const int*   edge_index = (const int*)d_in[0];   // [2, NEDGES]: row0=dest, row1=src
    const int*   etype      = (const int*)d_in[1];
    const float* emb        = (const float*)d_in[2];
    const float* W          = (const float*)d_in[3]; // [3,9,128,128]
    const float* Bias       = (const float*)d_in[4]; // [3,9,128]
    float*       out        = (float*)d_out;

    const int* dst  = edge_index;
    const int* srcA = edge_index + NEDGES;

    // ws layout
    float* HA = (float*)d_ws;                               // 50000*128 f32
    float* HB = HA + (size_t)NNODES * HID;                  // 50000*128 f32
    short* Wt = (short*)(HB + (size_t)NNODES * HID);        // 27*128*128 bf16
    int*   bsrc     = (int*)(Wt + (size_t)NLAYERS * NREL * HID * HID);
    int*   bins     = bsrc + NEDGES;
    int*   cursor   = bins + NBINS;
    int*   rowptr   = cursor + NBINS;                       // NBINS+1
    int*   blocksum = rowptr + NBINS + 1;
    int*   blockoff = blocksum + NBLK;

    hipMemsetAsync(bins, 0, NBINS * sizeof(int), stream);
    hist2_kernel<<<(NEDGES + 255) / 256, 256, 0, stream>>>(dst, etype, bins);
    scan_pass1<<<NBLK, 256, 0, stream>>>(bins, blocksum);
    scan_pass2<<<1, 512, 0, stream>>>(blocksum, blockoff, rowptr);
    scan_pass3<<<NBLK, 256, 0, stream>>>(bins, blockoff, rowptr, cursor);
    place_kernel<<<(NEDGES + 255) / 256, 256, 0, stream>>>(dst, srcA, etype, cursor, bsrc);
    convert_w<<<NLAYERS * NREL, 256, 0, stream>>>(W, Wt);

    const float* Hin = emb;
    for (int l = 0; l < NLAYERS; l++) {
        float* Hout = (l == 0) ? HA : ((l == 1) ? HB : out);
        const short* Wtl = Wt + (size_t)l * NREL * HID * HID;
        const float* Bl  = Bias + (size_t)l * NREL * HID;
        fused_layer<<<(NNODES + GM - 1) / GM, 256, 0, stream>>>(
            Hin, Wtl, Bl, bsrc, rowptr, Hout, (l + 1 < NLAYERS) ? 1 : 0);
        Hin = Hout;
    }
}